// Round 3
// baseline (357.211 us; speedup 1.0000x reference)
//
#include <hip/hip_runtime.h>
#include <cstdint>

// Problem constants (from the reference)
#define NF 23
#define ED 16
static const long long VTOT = 205470;
#define NPAIR 253            // NF*(NF-1)/2

__constant__ int OFFSETS_D[NF] = {
    0, 1000, 51000, 71000, 81000, 86000, 88000, 89000, 89500, 189500,
    197500, 201500, 203500, 204500, 205000, 205250, 205350, 205400,
    205430, 205450, 205460, 205465, 205468
};

struct PairTab { unsigned char pi[256]; unsigned char pj[256]; };
static constexpr PairTab make_pairs() {
    PairTab t{};
    int p = 0;
    for (int i = 0; i < NF; ++i)
        for (int j = i + 1; j < NF; ++j) { t.pi[p] = (unsigned char)i; t.pj[p] = (unsigned char)j; ++p; }
    for (; p < 256; ++p) { t.pi[p] = 0; t.pj[p] = 1; }
    return t;
}
__constant__ PairTab PAIRS = make_pairs();

// One 64-lane wave per batch element. 4 waves per 256-thread block.
// Lane layout per iteration: 16 pairs in flight, 4 lanes per pair,
// each lane handles one float4 (4 of the 16 embed dims).
__global__ __launch_bounds__(256) void ffm_kernel(
    const int* __restrict__ x,      // [B, NF] per-field indices
    const float* __restrict__ E,    // [NF, VTOT, ED]
    const float* __restrict__ W,    // [VTOT, 1]
    const float* __restrict__ bias, // [1]
    float* __restrict__ out,        // [B]
    int B)
{
    __shared__ int s_idx[4][NF];

    const int lane = threadIdx.x & 63;
    const int wid  = threadIdx.x >> 6;
    const int b    = blockIdx.x * 4 + wid;
    const bool valid_b = (b < B);

    float acc = 0.0f;

    // Stage global indices for this wave's batch element; fold linear term
    // into the accumulator (lanes 0..22).
    if (valid_b && lane < NF) {
        int ix = x[(long long)b * NF + lane] + OFFSETS_D[lane];
        s_idx[wid][lane] = ix;
        acc = W[ix];
    }
    __syncthreads();

    if (valid_b) {
        const int grp = lane >> 2;   // which pair within the iteration (0..15)
        const int dq  = lane & 3;    // which float4 of the 16-d vector

        #pragma unroll 4
        for (int it = 0; it < 16; ++it) {
            const int p = it * 16 + grp;
            if (p < NPAIR) {
                const int i = PAIRS.pi[p];
                const int j = PAIRS.pj[p];
                const long long idx_i = s_idx[wid][i];
                const long long idx_j = s_idx[wid][j];
                const float4 a = *reinterpret_cast<const float4*>(
                    E + ((long long)i * VTOT + idx_j) * ED + dq * 4);
                const float4 c = *reinterpret_cast<const float4*>(
                    E + ((long long)j * VTOT + idx_i) * ED + dq * 4);
                acc += a.x * c.x + a.y * c.y + a.z * c.z + a.w * c.w;
            }
        }
    }

    // Full 64-lane reduction: sums 253 pair-dots + 23 linear partials.
    #pragma unroll
    for (int off = 32; off; off >>= 1) acc += __shfl_xor(acc, off, 64);

    if (valid_b && lane == 0) {
        const float z = acc + bias[0];
        out[b] = 1.0f / (1.0f + __expf(-z));
    }
}

extern "C" void kernel_launch(void* const* d_in, const int* in_sizes, int n_in,
                              void* d_out, int out_size, void* d_ws, size_t ws_size,
                              hipStream_t stream) {
    const int*   x    = (const int*)d_in[0];    // [B, NF] int32
    const float* E    = (const float*)d_in[1];  // [NF, VTOT, ED] f32
    const float* W    = (const float*)d_in[2];  // [VTOT, 1] f32
    const float* bias = (const float*)d_in[3];  // [1] f32
    float* out = (float*)d_out;

    const int B = in_sizes[0] / NF;
    const int blocks = (B + 3) / 4;
    ffm_kernel<<<blocks, 256, 0, stream>>>(x, E, W, bias, out, B);
}